// Round 1
// baseline (14330.566 us; speedup 1.0000x reference)
//
#include <hip/hip_runtime.h>
#include <math.h>

// ConvLSTM: B=4, T=16, C=1, H=W=64, HID=64, two layers, k=3 SAME.
// Layer0: conv([x(1ch), h0(64ch)]) -> 256ch gates ; Layer1: conv([h0, h1]) -> 256ch.
// Strategy: fp32 direct conv as tiled implicit GEMM.
//   block = 256 threads = 16x16 pixel tile; computes HCG=8 hid channels x 4 gates.
//   Input halo tile (CI_CHUNK x 18x18) staged in LDS; weights via wave-uniform
//   loads (scalar pipe). LSTM pointwise fused into epilogue.
// States in d_ws: h0/h1 double-buffered (halo race), c0/c1 in-place.

#define HID 64
#define Hh 64
#define Ww 64
#define Bb 4
#define Tt 16
constexpr int PIX = Hh * Ww;          // 4096
constexpr int HCG = 8;                // hid channels per block
constexpr int CI_CHUNK = 8;           // input channels staged per LDS pass
constexpr int LDSW = 18;              // 16 + 2 halo
constexpr int LDSA = LDSW * LDSW;     // 324

__device__ __forceinline__ float sigm(float x) {
    return 1.f / (1.f + __expf(-x));
}
__device__ __forceinline__ float tanh_fast(float x) {
    // 1 - 2/(exp(2x)+1); saturates correctly at +-inf
    float e = __expf(2.f * x);
    return 1.f - 2.f / (e + 1.f);
}

template <int CIN>
__device__ __forceinline__ void accum_ci(const float* __restrict__ wgt,
                                         const float* __restrict__ sp, // &s_in[c][0]
                                         int py, int px, int ci, int hc0,
                                         float (&acc)[4][HCG]) {
    float in[9];
#pragma unroll
    for (int dy = 0; dy < 3; ++dy)
#pragma unroll
        for (int dx = 0; dx < 3; ++dx)
            in[dy * 3 + dx] = sp[(py + dy) * LDSW + px + dx];
#pragma unroll
    for (int g = 0; g < 4; ++g)
#pragma unroll
        for (int h = 0; h < HCG; ++h) {
            // co = g*64 + hc0 + h ; address is wave-uniform -> scalar loads
            const float* wc = wgt + ((size_t)((g * 64 + hc0 + h) * CIN + ci)) * 9;
#pragma unroll
            for (int k = 0; k < 9; ++k)
                acc[g][h] = fmaf(wc[k], in[k], acc[g][h]);
        }
}

template <int CIN_A>
__global__ __launch_bounds__(256, 2) void cell_kernel(
    const float* __restrict__ inA, int strideA_b,   // layer0: x_t (b-stride T*PIX); layer1: h0 (b-stride HID*PIX)
    const float* __restrict__ inB,                  // h_prev of this layer [B][HID][H][W]
    const float* __restrict__ wgt,                  // [256][CIN_A+HID][3][3]
    const float* __restrict__ bias,                 // [256]
    float* __restrict__ c_state,                    // in-place [B][HID][H][W]
    float* __restrict__ h_out,                      // write buffer [B][HID][H][W]
    float* __restrict__ out)                        // null, or d_out + t*HID*PIX
{
    constexpr int CIN = CIN_A + HID;
    __shared__ float s_in[CI_CHUNK][LDSA];

    const int tid = threadIdx.x;
    const int px = tid & 15, py = tid >> 4;
    const int b = blockIdx.x >> 4;
    const int tile = blockIdx.x & 15;
    const int by = (tile >> 2) << 4, bx = (tile & 3) << 4;
    const int hc0 = blockIdx.y * HCG;

    float acc[4][HCG];
#pragma unroll
    for (int g = 0; g < 4; ++g)
#pragma unroll
        for (int h = 0; h < HCG; ++h)
            acc[g][h] = bias[g * 64 + hc0 + h];

    const int gy0 = by - 1, gx0 = bx - 1;

    for (int ci0 = 0; ci0 < CIN; ci0 += CI_CHUNK) {
        const int nch = (CIN - ci0 < CI_CHUNK) ? (CIN - ci0) : CI_CHUNK;
        const int total = nch * LDSA;
        for (int e = tid; e < total; e += 256) {
            int ch = e / LDSA;
            int rem = e - ch * LDSA;
            int iy = rem / LDSW;
            int ix = rem - iy * LDSW;
            int gy = gy0 + iy, gx = gx0 + ix;
            float v = 0.f;
            if ((unsigned)gy < (unsigned)Hh && (unsigned)gx < (unsigned)Ww) {
                int ci = ci0 + ch;
                if (ci < CIN_A)
                    v = inA[(size_t)b * strideA_b + ci * PIX + gy * Ww + gx];
                else
                    v = inB[(size_t)(b * HID + (ci - CIN_A)) * PIX + gy * Ww + gx];
            }
            s_in[0][e] = v;
        }
        __syncthreads();

        if (nch == CI_CHUNK) {
#pragma unroll
            for (int c = 0; c < CI_CHUNK; ++c)
                accum_ci<CIN>(wgt, &s_in[c][0], py, px, ci0 + c, hc0, acc);
        } else {
            for (int c = 0; c < nch; ++c)
                accum_ci<CIN>(wgt, &s_in[c][0], py, px, ci0 + c, hc0, acc);
        }
        __syncthreads();
    }

    // fused LSTM epilogue: i,f,o,g = gate blocks 0..3
    const int pix = (by + py) * Ww + (bx + px);
#pragma unroll
    for (int h = 0; h < HCG; ++h) {
        int hc = hc0 + h;
        size_t idx = (size_t)(b * HID + hc) * PIX + pix;
        float ig = sigm(acc[0][h]);
        float fg = sigm(acc[1][h]);
        float og = sigm(acc[2][h]);
        float gg = tanh_fast(acc[3][h]);
        float c = fg * c_state[idx] + ig * gg;
        float hh = og * tanh_fast(c);
        c_state[idx] = c;
        h_out[idx] = hh;
        if (out) out[(size_t)(b * (Tt * HID) + hc) * PIX + pix] = hh;
    }
}

extern "C" void kernel_launch(void* const* d_in, const int* in_sizes, int n_in,
                              void* d_out, int out_size, void* d_ws, size_t ws_size,
                              hipStream_t stream) {
    const float* x = (const float*)d_in[0];    // [B][T][1][H][W]
    const float* w0 = (const float*)d_in[1];   // [256][65][3][3]
    const float* b0 = (const float*)d_in[2];   // [256]
    const float* w1 = (const float*)d_in[3];   // [256][128][3][3]
    const float* b1 = (const float*)d_in[4];   // [256]
    float* out = (float*)d_out;                // [B][T][HID][H][W]

    float* ws = (float*)d_ws;
    const size_t SB = (size_t)Bb * HID * PIX;  // 1,048,576 floats per state
    float* h0a = ws + 0 * SB;
    float* h0b = ws + 1 * SB;
    float* h1a = ws + 2 * SB;
    float* h1b = ws + 3 * SB;
    float* c0 = ws + 4 * SB;
    float* c1 = ws + 5 * SB;
    // zero-init all states (ws is poisoned 0xAA before every timed launch)
    hipMemsetAsync(d_ws, 0, 6 * SB * sizeof(float), stream);

    dim3 grid(Bb * 16, HID / HCG);  // (64, 8) = 512 blocks
    dim3 blk(256);
    for (int t = 0; t < Tt; ++t) {
        float* h0r = (t & 1) ? h0b : h0a;
        float* h0w = (t & 1) ? h0a : h0b;
        float* h1r = (t & 1) ? h1b : h1a;
        float* h1w = (t & 1) ? h1a : h1b;
        const float* xt = x + (size_t)t * PIX;  // b-stride = T*PIX
        cell_kernel<1><<<grid, blk, 0, stream>>>(xt, Tt * PIX, h0r, w0, b0, c0,
                                                 h0w, nullptr);
        cell_kernel<HID><<<grid, blk, 0, stream>>>(h0w, HID * PIX, h1r, w1, b1,
                                                   c1, h1w,
                                                   out + (size_t)t * HID * PIX);
    }
}

// Round 2
// 2229.096 us; speedup vs baseline: 6.4289x; 6.4289x over previous
//
#include <hip/hip_runtime.h>

// ConvLSTM B=4 T=16 C=1 H=W=64 HID=64, 2 layers, k=3 SAME.
// bf16 MFMA implicit-GEMM: per (t,layer) kernel computes 256 gate channels.
// Block (256 thr, 4 waves) = 16x16 pixel tile x 16 hid ch x 4 gates.
//   wave = 4 pixel rows; Mtiles = 4 gates (so i,f,o,g land in the same thread
//   regs -> fused LSTM epilogue); Ntiles = 4 rows of 16 px.
// K-loop: 32-ch chunks x 9 taps. Input halo (18x18) staged bf16 in LDS
//   [324 px][40 el stride]; weights prepacked to A-frag layout and staged.
// States: h0/h1 bf16 double-buffered in ws; c0/c1 fp32 in-place.

typedef __attribute__((ext_vector_type(8))) short short8;
typedef __attribute__((ext_vector_type(4))) float float4v;
typedef unsigned short ushort_t;
typedef unsigned int uint_t;

#define HID 64
constexpr int PIX = 4096;     // 64*64
constexpr int LDSW = 18;      // 16 + halo
constexpr int HALO = 324;     // 18*18
constexpr int SPAD = 40;      // sIn element stride per pixel (16B-aligned, low-conflict)

__device__ __forceinline__ ushort_t f2b(float f) {
    uint_t u = __float_as_uint(f);
    return (ushort_t)((u + 0x7fffu + ((u >> 16) & 1u)) >> 16);  // RNE
}
__device__ __forceinline__ float sigm(float x) { return 1.f / (1.f + __expf(-x)); }
__device__ __forceinline__ float tanh_fast(float x) {
    float e = __expf(2.f * x);
    return 1.f - 2.f / (e + 1.f);
}

// Prepack weights: w[256][CIN][3][3] fp32 -> Wp bf16, element index
// e = (((tap*CGP + cg)*4 + g)*64 + hid)*8 + j  with channel c = cg*8+j (0 if c>=CIN)
template <int CIN, int CGP>
__global__ void pack_w(const float* __restrict__ w, ushort_t* __restrict__ Wp, int total) {
    int e = blockIdx.x * 256 + threadIdx.x;
    if (e >= total) return;
    int j = e & 7, hid = (e >> 3) & 63, g = (e >> 9) & 3;
    int rem = e >> 11;
    int cg = rem % CGP, tap = rem / CGP;
    int c = cg * 8 + j;
    float val = (c < CIN) ? w[((g * 64 + hid) * CIN + c) * 9 + tap] : 0.f;
    Wp[e] = f2b(val);
}

__global__ void cvt_bf16(const float* __restrict__ src, ushort_t* __restrict__ dst, int n) {
    int i = blockIdx.x * 256 + threadIdx.x;
    if (i < n) dst[i] = f2b(src[i]);
}

template <int CIN_A>
__global__ __launch_bounds__(256, 1) void cell_mfma(
    const ushort_t* __restrict__ inA, int bstrA,  // layer0: x_t bf16; layer1: h0 bf16
    const ushort_t* __restrict__ inB,             // h_prev of this layer, bf16
    const ushort_t* __restrict__ Wp,              // prepacked weights bf16
    const float* __restrict__ bias,               // [256] fp32
    float* __restrict__ cst,                      // c state fp32, in-place
    ushort_t* __restrict__ hnext,                 // h out bf16
    float* __restrict__ out)                      // null, or d_out + t*HID*PIX
{
    constexpr int CINV = CIN_A + HID;             // 65 or 128
    constexpr int NCH = (CINV + 31) / 32;         // 3 or 4
    constexpr int CGP = NCH * 4;

    __shared__ __align__(16) ushort_t sIn[HALO * SPAD];      // 25920 B
    __shared__ __align__(16) ushort_t sW[9 * 4 * 4 * 16 * 8]; // 36864 B

    const int tid = threadIdx.x;
    const int lane = tid & 63;
    const int wq = tid >> 6;      // wave id = pixel row group (4 rows each)
    const int x = lane & 15;      // MFMA row/col-in-16
    const int q = lane >> 4;      // MFMA k-group
    const int b = blockIdx.x >> 4;
    const int pt = blockIdx.x & 15;
    const int by = (pt >> 2) << 4, bx = (pt & 3) << 4;
    const int hg = blockIdx.y;    // hid group (16 ch)

    // acc[m][nt]: m = gate, nt = pixel row within wave; init with bias
    float4v acc[4][4];
#pragma unroll
    for (int m = 0; m < 4; ++m) {
        float4v bv;
#pragma unroll
        for (int r = 0; r < 4; ++r)
            bv[r] = bias[m * 64 + hg * 16 + q * 4 + r];
#pragma unroll
        for (int nt = 0; nt < 4; ++nt) acc[m][nt] = bv;
    }

    const int abase = q * 512 + x * 8;  // A-frag el base in sW
    int bb[4];                          // B-frag el bases in sIn (tap 0)
#pragma unroll
    for (int nt = 0; nt < 4; ++nt)
        bb[nt] = ((wq * 4 + nt) * LDSW + x) * SPAD + q * 8;

    for (int ck = 0; ck < NCH; ++ck) {
        // ---- stage input chunk: 32 ch x 324 halo px, bf16 -> sIn[p*SPAD + c]
        for (int i = tid; i < 32 * HALO; i += 256) {
            int c = i / HALO;
            int p = i - c * HALO;
            int iy = p / LDSW, ix = p - iy * LDSW;
            int gy = by - 1 + iy, gx = bx - 1 + ix;
            int ch = ck * 32 + c;
            ushort_t v = 0;
            if ((unsigned)gy < 64u && (unsigned)gx < 64u && ch < CINV)
                v = (ch < CIN_A)
                        ? inA[b * bstrA + ch * PIX + gy * 64 + gx]
                        : inB[(b * HID + (ch - CIN_A)) * PIX + gy * 64 + gx];
            sIn[p * SPAD + c] = v;
        }
        // ---- stage weights for this chunk: 2304 x 16B vector copies
        for (int v = tid; v < 9 * 256; v += 256) {
            int hidL = v & 15, g = (v >> 4) & 3, cg = (v >> 6) & 3, tap = v >> 8;
            int src = ((tap * CGP + ck * 4 + cg) * 4 + g) * 64 + hg * 16 + hidL;
            *(uint4*)&sW[(((tap * 4 + cg) * 4 + g) * 16 + hidL) * 8] =
                *(const uint4*)&Wp[src * 8];
        }
        __syncthreads();

#pragma unroll
        for (int tap = 0; tap < 9; ++tap) {
            const int dy = tap / 3, dx = tap - dy * 3;
            short8 a[4];
#pragma unroll
            for (int m = 0; m < 4; ++m)
                a[m] = *(const short8*)&sW[tap * 2048 + abase + m * 128];
#pragma unroll
            for (int nt = 0; nt < 4; ++nt) {
                short8 bf = *(const short8*)&sIn[bb[nt] + (dy * LDSW + dx) * SPAD];
#pragma unroll
                for (int m = 0; m < 4; ++m)
                    acc[m][nt] = __builtin_amdgcn_mfma_f32_16x16x32_bf16(
                        a[m], bf, acc[m][nt], 0, 0, 0);
            }
        }
        __syncthreads();
    }

    // ---- fused LSTM epilogue (gates i,f,o,g = m 0..3, all in this thread)
#pragma unroll
    for (int nt = 0; nt < 4; ++nt) {
        int px = (by + wq * 4 + nt) * 64 + bx + x;
#pragma unroll
        for (int r = 0; r < 4; ++r) {
            int hid = hg * 16 + q * 4 + r;
            int idx = (b * HID + hid) * PIX + px;
            float ig = sigm(acc[0][nt][r]);
            float fg = sigm(acc[1][nt][r]);
            float og = sigm(acc[2][nt][r]);
            float gg = tanh_fast(acc[3][nt][r]);
            float c = fg * cst[idx] + ig * gg;
            float h = og * tanh_fast(c);
            cst[idx] = c;
            hnext[idx] = f2b(h);
            if (out) out[b * (16 * HID * PIX) + hid * PIX + px] = h;
        }
    }
}

extern "C" void kernel_launch(void* const* d_in, const int* in_sizes, int n_in,
                              void* d_out, int out_size, void* d_ws, size_t ws_size,
                              hipStream_t stream) {
    const float* xf = (const float*)d_in[0];  // [4][16][1][64][64]
    const float* w0 = (const float*)d_in[1];  // [256][65][3][3]
    const float* b0 = (const float*)d_in[2];
    const float* w1 = (const float*)d_in[3];  // [256][128][3][3]
    const float* b1 = (const float*)d_in[4];
    float* out = (float*)d_out;               // [4][16][64][64][64]

    char* ws = (char*)d_ws;
    const size_t SBH = (size_t)4 * HID * PIX;           // 1,048,576 elems
    ushort_t* h0a = (ushort_t*)ws;                      // 2 MB each
    ushort_t* h0b = h0a + SBH;
    ushort_t* h1a = h0b + SBH;
    ushort_t* h1b = h1a + SBH;
    float* c0 = (float*)(ws + 4 * SBH * sizeof(ushort_t));  // +8MB, 4MB each
    float* c1 = c0 + SBH;
    ushort_t* xbf = (ushort_t*)(ws + 16u * 1024 * 1024);    // 262144 elems
    ushort_t* Wp0 = xbf + 262144;                           // 221184 elems
    ushort_t* Wp1 = Wp0 + 221184;                           // 294912 elems

    // zero h (bf16 x4, 8MB) + c (fp32 x2, 8MB): contiguous 16MB
    hipMemsetAsync(ws, 0, 16u * 1024 * 1024, stream);

    cvt_bf16<<<262144 / 256, 256, 0, stream>>>(xf, xbf, 262144);
    pack_w<65, 12><<<(221184 + 255) / 256, 256, 0, stream>>>(w0, Wp0, 221184);
    pack_w<128, 16><<<(294912 + 255) / 256, 256, 0, stream>>>(w1, Wp1, 294912);

    dim3 grid(64, 4), blk(256);
    for (int t = 0; t < 16; ++t) {
        ushort_t* h0r = (t & 1) ? h0b : h0a;
        ushort_t* h0w = (t & 1) ? h0a : h0b;
        ushort_t* h1r = (t & 1) ? h1b : h1a;
        ushort_t* h1w = (t & 1) ? h1a : h1b;
        cell_mfma<1><<<grid, blk, 0, stream>>>(xbf + t * PIX, 16 * PIX, h0r, Wp0,
                                               b0, c0, h0w, nullptr);
        cell_mfma<HID><<<grid, blk, 0, stream>>>(h0w, HID * PIX, h1r, Wp1, b1, c1,
                                                 h1w, out + (size_t)t * HID * PIX);
    }
}

// Round 4
// 728.380 us; speedup vs baseline: 19.6746x; 3.0603x over previous
//
#include <hip/hip_runtime.h>

// ConvLSTM B=4 T=16 C=1 H=W=64 HID=64, 2 layers, k=3 SAME.
// bf16 MFMA implicit-GEMM, round 3: staging rewrite.
//  - states/x in PADDED bf16 layout [.][ch][66][72] (zero border) ->
//    halo staging = aligned short8 loads, no bounds checks.
//  - weights prepacked per (hg,chunk) contiguous -> async global_load_lds x16B.
//  - reg-prefetch ping-pong (VA/VB) to hide global latency under ds_writes.
// Block (256 thr, 4 waves) = 16x16 px tile x 16 hid x 4 gates; wave tile 64x64.

typedef __attribute__((ext_vector_type(8))) short short8;
typedef __attribute__((ext_vector_type(4))) float float4v;
typedef unsigned short ushort_t;
typedef unsigned int uint_t;

#define HID 64
constexpr int PIX = 4096;
constexpr int HP = 72;                 // padded row stride (els)
constexpr int PROWS = 66;              // rows: y=-1..64
constexpr int PIMG = HP * PROWS;       // 4752 els per padded plane
constexpr int LDSW = 18;
constexpr int HALO = 324;              // 18*18
constexpr int SPAD = 40;               // sIn stride per pixel (els)
constexpr int WCHUNK = 18432;          // weight els per (hg, chunk)

__device__ __forceinline__ ushort_t f2b(float f) {
    uint_t u = __float_as_uint(f);
    return (ushort_t)((u + 0x7fffu + ((u >> 16) & 1u)) >> 16);  // RNE
}
__device__ __forceinline__ float sigm(float x) { return 1.f / (1.f + __expf(-x)); }
__device__ __forceinline__ float tanh_fast(float x) {
    float e = __expf(2.f * x);
    return 1.f - 2.f / (e + 1.f);
}
__device__ __forceinline__ void gl_lds16(const ushort_t* g, ushort_t* l) {
    __builtin_amdgcn_global_load_lds(
        (const __attribute__((address_space(1))) unsigned int*)g,
        (__attribute__((address_space(3))) unsigned int*)l, 16, 0, 0);
}

// x [4][16][64][64] f32 -> padded bf16 planes [b*16+t][66][72] (pre-zeroed)
__global__ void cvt_pad_x(const float* __restrict__ src, ushort_t* __restrict__ dst) {
    int i = blockIdx.x * 256 + threadIdx.x;  // 262144
    int bt = i >> 12, p = i & 4095, y = p >> 6, xx = p & 63;
    dst[bt * PIMG + (y + 1) * HP + xx + 1] = f2b(src[i]);
}

// Wp layout: [hg][ck][tap][cg][gate][hid16][8j]; channel c = ck*32+cg*8+j.
// L0: our channel order = [h(0..63), x, zeros]; w's order = [x, h(0..63)].
template <int CIN, int NCH, bool L0>
__global__ void pack_w(const float* __restrict__ w, ushort_t* __restrict__ Wp, int total) {
    int e = blockIdx.x * 256 + threadIdx.x;
    if (e >= total) return;
    int j = e & 7;
    int hidL = (e >> 3) & 15;
    int g = (e >> 7) & 3;
    int cg = (e >> 9) & 3;
    int r = e >> 11;
    int tap = r % 9; r /= 9;
    int ck = r % NCH;
    int hg = r / NCH;
    int c = ck * 32 + cg * 8 + j;
    int outc = g * 64 + hg * 16 + hidL;
    int wch;
    if (L0) wch = (c < 64) ? c + 1 : (c == 64 ? 0 : -1);
    else    wch = (c < CIN) ? c : -1;
    Wp[e] = (wch >= 0) ? f2b(w[(outc * CIN + wch) * 9 + tap]) : (ushort_t)0;
}

// ---- staging helpers (jobs: 576 = 18 halo rows x 32 ch) ----
template <int CINV>
__device__ __forceinline__ void stage_load(const ushort_t* __restrict__ srcA,
                                           const ushort_t* __restrict__ srcB,
                                           int bstrB, int ck, int b, int by, int bx,
                                           int tid, short8 (&V)[3][3]) {
#pragma unroll
    for (int jj = 0; jj < 3; ++jj) {
        int job = tid + jj * 256;
        if (job < 576) {
            int hrow = job >> 5, ch = job & 31;
            int gch = ck * 32 + ch;
            const ushort_t* p = nullptr;
            if (gch < 64)
                p = srcA + (size_t)(b * 64 + gch) * PIMG;
            else if (gch < CINV)
                p = srcB + (size_t)b * bstrB + (size_t)(gch - 64) * PIMG;
            if (p) {
                p += (by + hrow) * HP + bx;  // padded row=by+hrow, col=bx (8-aligned)
                V[jj][0] = *(const short8*)(p);
                V[jj][1] = *(const short8*)(p + 8);
                V[jj][2] = *(const short8*)(p + 16);
            } else {
                short8 z = {};
                V[jj][0] = z; V[jj][1] = z; V[jj][2] = z;
            }
        }
    }
}

__device__ __forceinline__ void stage_write(ushort_t* __restrict__ sIn, int tid,
                                            short8 (&V)[3][3]) {
#pragma unroll
    for (int jj = 0; jj < 3; ++jj) {
        int job = tid + jj * 256;
        if (job < 576) {
            int hrow = job >> 5, ch = job & 31;
            ushort_t* dst = sIn + hrow * LDSW * SPAD + ch;
#pragma unroll
            for (int k = 0; k < 3; ++k)
#pragma unroll
                for (int ii = 0; ii < 8; ++ii) {
                    int hx = k * 8 + ii;
                    if (hx < 18) dst[hx * SPAD] = (ushort_t)V[jj][k][ii];
                }
        }
    }
}

template <int CINV, int NCH>
__global__ __launch_bounds__(256, 1) void cell_mfma(
    const ushort_t* __restrict__ srcA,  // padded, channels [0,64)
    const ushort_t* __restrict__ srcB,  // padded, channels [64,CINV)
    int bstrB,
    const ushort_t* __restrict__ Wp,
    const float* __restrict__ bias,
    float* __restrict__ cst,
    ushort_t* __restrict__ hnext,       // padded
    float* __restrict__ out)            // null, or d_out + t*HID*PIX
{
    __shared__ __align__(16) ushort_t sIn[HALO * SPAD];  // 25920 B
    __shared__ __align__(16) ushort_t sW[WCHUNK];        // 36864 B

    const int tid = threadIdx.x;
    const int lane = tid & 63;
    const int wq = tid >> 6;
    const int x = lane & 15;
    const int q = lane >> 4;
    const int b = blockIdx.x >> 4;
    const int pt = blockIdx.x & 15;
    const int by = (pt >> 2) << 4, bx = (pt & 3) << 4;
    const int hg = blockIdx.y;

    float4v acc[4][4];
#pragma unroll
    for (int m = 0; m < 4; ++m) {
        float4v bv;
#pragma unroll
        for (int r = 0; r < 4; ++r) bv[r] = bias[m * 64 + hg * 16 + q * 4 + r];
#pragma unroll
        for (int nt = 0; nt < 4; ++nt) acc[m][nt] = bv;
    }

    const int abase = q * 512 + x * 8;
    int bb[4];
#pragma unroll
    for (int nt = 0; nt < 4; ++nt)
        bb[nt] = ((wq * 4 + nt) * LDSW + x) * SPAD + q * 8;

    const ushort_t* wbase = Wp + (size_t)hg * NCH * WCHUNK;

#define STAGE_W(ck)                                                          \
    {                                                                        \
        const ushort_t* wsrc = wbase + (ck) * WCHUNK;                        \
        _Pragma("unroll") for (int k = 0; k < 9; ++k)                        \
            gl_lds16(wsrc + (k * 256 + tid) * 8, &sW[(k * 256 + tid) * 8]);  \
    }

#define COMPUTE()                                                            \
    {                                                                        \
        _Pragma("unroll") for (int tap = 0; tap < 9; ++tap) {                \
            const int dy = tap / 3, dxo = tap - dy * 3;                      \
            short8 a[4];                                                     \
            const ushort_t* wp_ = sW + tap * 2048 + abase;                   \
            _Pragma("unroll") for (int m = 0; m < 4; ++m)                    \
                a[m] = *(const short8*)(wp_ + m * 128);                      \
            _Pragma("unroll") for (int nt = 0; nt < 4; ++nt) {               \
                short8 bf = *(const short8*)&sIn[bb[nt] + (dy * LDSW + dxo) * SPAD]; \
                _Pragma("unroll") for (int m = 0; m < 4; ++m)                \
                    acc[m][nt] = __builtin_amdgcn_mfma_f32_16x16x32_bf16(    \
                        a[m], bf, acc[m][nt], 0, 0, 0);                      \
            }                                                                \
        }                                                                    \
    }

    short8 VA[3][3], VB[3][3];
    stage_load<CINV>(srcA, srcB, bstrB, 0, b, by, bx, tid, VA);
#pragma unroll
    for (int ck = 0; ck < NCH; ck += 2) {
        __syncthreads();
        if (ck + 1 < NCH)
            stage_load<CINV>(srcA, srcB, bstrB, ck + 1, b, by, bx, tid, VB);
        stage_write(sIn, tid, VA);
        STAGE_W(ck);
        __syncthreads();
        COMPUTE();
        if (ck + 1 < NCH) {
            __syncthreads();
            if (ck + 2 < NCH)
                stage_load<CINV>(srcA, srcB, bstrB, ck + 2, b, by, bx, tid, VA);
            stage_write(sIn, tid, VB);
            STAGE_W(ck + 1);
            __syncthreads();
            COMPUTE();
        }
    }

    // fused LSTM epilogue: m = gate (i,f,o,g)
#pragma unroll
    for (int nt = 0; nt < 4; ++nt) {
        int iy = by + wq * 4 + nt, ix = bx + x;
        int px = iy * 64 + ix;
#pragma unroll
        for (int r = 0; r < 4; ++r) {
            int hid = hg * 16 + q * 4 + r;
            int idx = (b * HID + hid) * PIX + px;
            float ig = sigm(acc[0][nt][r]);
            float fg = sigm(acc[1][nt][r]);
            float og = sigm(acc[2][nt][r]);
            float gg = tanh_fast(acc[3][nt][r]);
            float c = fg * cst[idx] + ig * gg;
            float h = og * tanh_fast(c);
            cst[idx] = c;
            hnext[(size_t)(b * HID + hid) * PIMG + (iy + 1) * HP + ix + 1] = f2b(h);
            if (out) out[(size_t)b * (16 * HID * PIX) + (size_t)hid * PIX + px] = h;
        }
    }
#undef STAGE_W
#undef COMPUTE
}

extern "C" void kernel_launch(void* const* d_in, const int* in_sizes, int n_in,
                              void* d_out, int out_size, void* d_ws, size_t ws_size,
                              hipStream_t stream) {
    const float* xf = (const float*)d_in[0];  // [4][16][1][64][64]
    const float* w0 = (const float*)d_in[1];  // [256][65][3][3]
    const float* b0 = (const float*)d_in[2];
    const float* w1 = (const float*)d_in[3];  // [256][128][3][3]
    const float* b1 = (const float*)d_in[4];
    float* out = (float*)d_out;               // [4][16][64][64][64]

    char* ws = (char*)d_ws;
    const size_t HBUF = (size_t)4 * HID * PIMG;       // 1,216,512 els
    ushort_t* h0a = (ushort_t*)ws;
    ushort_t* h0b = h0a + HBUF;
    ushort_t* h1a = h0b + HBUF;
    ushort_t* h1b = h1a + HBUF;
    ushort_t* xpad = h1b + HBUF;                      // 4*16*PIMG = 304,128 els
    float* c0 = (float*)(xpad + (size_t)4 * 16 * PIMG);
    float* c1 = c0 + (size_t)4 * HID * PIX;           // 1,048,576 f32 each
    ushort_t* Wp0 = (ushort_t*)(c1 + (size_t)4 * HID * PIX);  // 221,184 els
    ushort_t* Wp1 = Wp0 + 221184;                             // 294,912 els

    // zero h(x4, padded) + xpad + c0 + c1 : one contiguous region
    size_t zbytes = (4 * HBUF + (size_t)4 * 16 * PIMG) * sizeof(ushort_t) +
                    (size_t)2 * 4 * HID * PIX * sizeof(float);
    hipMemsetAsync(d_ws, 0, zbytes, stream);

    cvt_pad_x<<<262144 / 256, 256, 0, stream>>>(xf, xpad);
    pack_w<65, 3, true><<<221184 / 256, 256, 0, stream>>>(w0, Wp0, 221184);
    pack_w<128, 4, false><<<294912 / 256, 256, 0, stream>>>(w1, Wp1, 294912);

    dim3 grid(64, 4), blk(256);
    for (int t = 0; t < 16; ++t) {
        ushort_t* h0r = (t & 1) ? h0b : h0a;
        ushort_t* h0w = (t & 1) ? h0a : h0b;
        ushort_t* h1r = (t & 1) ? h1b : h1a;
        ushort_t* h1w = (t & 1) ? h1a : h1b;
        // layer0: channels [h0(64), x(1)] ; srcB = x plane for (b,t)
        cell_mfma<65, 3><<<grid, blk, 0, stream>>>(
            h0r, xpad + (size_t)t * PIMG, 16 * PIMG, Wp0, b0, c0, h0w, nullptr);
        // layer1: channels [h0(64), h1(64)]
        cell_mfma<128, 4><<<grid, blk, 0, stream>>>(
            h0w, h1r, HID * PIMG, Wp1, b1, c1, h1w,
            out + (size_t)t * HID * PIX);
    }
}

// Round 5
// 652.460 us; speedup vs baseline: 21.9639x; 1.1164x over previous
//
#include <hip/hip_runtime.h>

// ConvLSTM B=4 T=16 C=1 H=W=64 HID=64, 2 layers, k=3 SAME.
// Round 5: 2 blocks/CU. Pixel tile 16x16 -> 8x16, grid 256 -> 512 blocks,
// LDS 63 -> 51 KB, acc[4][4] -> acc[4][2]. Cross-block overlap hides staging.
// Block (256 thr, 4 waves) = 8x16 px tile x 16 hid x 4 gates.

typedef __attribute__((ext_vector_type(8))) short short8;
typedef __attribute__((ext_vector_type(4))) float float4v;
typedef unsigned short ushort_t;
typedef unsigned int uint_t;

#define HID 64
constexpr int PIX = 4096;
constexpr int HP = 72;                 // padded row stride (els)
constexpr int PROWS = 66;              // rows: y=-1..64
constexpr int PIMG = HP * PROWS;       // 4752 els per padded plane
constexpr int LDSW = 18;               // halo cols
constexpr int HROWS = 10;              // halo rows (8 + 2)
constexpr int HALO = HROWS * LDSW;     // 180
constexpr int SPAD = 40;               // sIn stride per pixel (els)
constexpr int WCHUNK = 18432;          // weight els per (hg, chunk)
constexpr int NJOBS = HROWS * 32;      // 320 staging jobs

__device__ __forceinline__ ushort_t f2b(float f) {
    uint_t u = __float_as_uint(f);
    return (ushort_t)((u + 0x7fffu + ((u >> 16) & 1u)) >> 16);  // RNE
}
__device__ __forceinline__ float sigm(float x) { return 1.f / (1.f + __expf(-x)); }
__device__ __forceinline__ float tanh_fast(float x) {
    float e = __expf(2.f * x);
    return 1.f - 2.f / (e + 1.f);
}
__device__ __forceinline__ void gl_lds16(const ushort_t* g, ushort_t* l) {
    __builtin_amdgcn_global_load_lds(
        (const __attribute__((address_space(1))) unsigned int*)g,
        (__attribute__((address_space(3))) unsigned int*)l, 16, 0, 0);
}

// x [4][16][64][64] f32 -> padded bf16 planes [b*16+t][66][72] (pre-zeroed)
__global__ void cvt_pad_x(const float* __restrict__ src, ushort_t* __restrict__ dst) {
    int i = blockIdx.x * 256 + threadIdx.x;  // 262144
    int bt = i >> 12, p = i & 4095, y = p >> 6, xx = p & 63;
    dst[bt * PIMG + (y + 1) * HP + xx + 1] = f2b(src[i]);
}

// Wp layout: [hg][ck][tap][cg][gate][hid16][8j]; channel c = ck*32+cg*8+j.
// L0: our channel order = [h(0..63), x, zeros]; w's order = [x, h(0..63)].
template <int CIN, int NCH, bool L0>
__global__ void pack_w(const float* __restrict__ w, ushort_t* __restrict__ Wp, int total) {
    int e = blockIdx.x * 256 + threadIdx.x;
    if (e >= total) return;
    int j = e & 7;
    int hidL = (e >> 3) & 15;
    int g = (e >> 7) & 3;
    int cg = (e >> 9) & 3;
    int r = e >> 11;
    int tap = r % 9; r /= 9;
    int ck = r % NCH;
    int hg = r / NCH;
    int c = ck * 32 + cg * 8 + j;
    int outc = g * 64 + hg * 16 + hidL;
    int wch;
    if (L0) wch = (c < 64) ? c + 1 : (c == 64 ? 0 : -1);
    else    wch = (c < CIN) ? c : -1;
    Wp[e] = (wch >= 0) ? f2b(w[(outc * CIN + wch) * 9 + tap]) : (ushort_t)0;
}

// ---- staging helpers (jobs: 320 = 10 halo rows x 32 ch) ----
template <int CINV>
__device__ __forceinline__ void stage_load(const ushort_t* __restrict__ srcA,
                                           const ushort_t* __restrict__ srcB,
                                           int bstrB, int ck, int b, int by, int bx,
                                           int tid, short8 (&V)[2][3]) {
#pragma unroll
    for (int jj = 0; jj < 2; ++jj) {
        int job = tid + jj * 256;
        if (job < NJOBS) {
            int hrow = job >> 5, ch = job & 31;
            int gch = ck * 32 + ch;
            const ushort_t* p = nullptr;
            if (gch < 64)
                p = srcA + (size_t)(b * 64 + gch) * PIMG;
            else if (gch < CINV)
                p = srcB + (size_t)b * bstrB + (size_t)(gch - 64) * PIMG;
            if (p) {
                p += (by + hrow) * HP + bx;  // padded row=by+hrow, col=bx (8-aligned)
                V[jj][0] = *(const short8*)(p);
                V[jj][1] = *(const short8*)(p + 8);
                V[jj][2] = *(const short8*)(p + 16);
            } else {
                short8 z = {};
                V[jj][0] = z; V[jj][1] = z; V[jj][2] = z;
            }
        }
    }
}

__device__ __forceinline__ void stage_write(ushort_t* __restrict__ sIn, int tid,
                                            short8 (&V)[2][3]) {
#pragma unroll
    for (int jj = 0; jj < 2; ++jj) {
        int job = tid + jj * 256;
        if (job < NJOBS) {
            int hrow = job >> 5, ch = job & 31;
            ushort_t* dst = sIn + hrow * LDSW * SPAD + ch;
#pragma unroll
            for (int k = 0; k < 3; ++k)
#pragma unroll
                for (int ii = 0; ii < 8; ++ii) {
                    int hx = k * 8 + ii;
                    if (hx < LDSW) dst[hx * SPAD] = (ushort_t)V[jj][k][ii];
                }
        }
    }
}

template <int CINV, int NCH>
__global__ __launch_bounds__(256, 2) void cell_mfma(
    const ushort_t* __restrict__ srcA,  // padded, channels [0,64)
    const ushort_t* __restrict__ srcB,  // padded, channels [64,CINV)
    int bstrB,
    const ushort_t* __restrict__ Wp,
    const float* __restrict__ bias,
    float* __restrict__ cst,
    ushort_t* __restrict__ hnext,       // padded
    float* __restrict__ out)            // null, or d_out + t*HID*PIX
{
    __shared__ __align__(16) ushort_t sIn[HALO * SPAD];  // 14400 B
    __shared__ __align__(16) ushort_t sW[WCHUNK];        // 36864 B

    const int tid = threadIdx.x;
    const int lane = tid & 63;
    const int wq = tid >> 6;
    const int x = lane & 15;
    const int q = lane >> 4;
    const int b = blockIdx.x >> 5;
    const int pt = blockIdx.x & 31;          // 8 row-tiles x 4 col-tiles
    const int by = (pt >> 2) << 3, bx = (pt & 3) << 4;
    const int hg = blockIdx.y;

    float4v acc[4][2];
#pragma unroll
    for (int m = 0; m < 4; ++m) {
        float4v bv;
#pragma unroll
        for (int r = 0; r < 4; ++r) bv[r] = bias[m * 64 + hg * 16 + q * 4 + r];
#pragma unroll
        for (int nt = 0; nt < 2; ++nt) acc[m][nt] = bv;
    }

    const int abase = q * 512 + x * 8;
    int bb[2];
#pragma unroll
    for (int nt = 0; nt < 2; ++nt)
        bb[nt] = ((wq * 2 + nt) * LDSW + x) * SPAD + q * 8;

    const ushort_t* wbase = Wp + (size_t)hg * NCH * WCHUNK;

#define STAGE_W(ck)                                                          \
    {                                                                        \
        const ushort_t* wsrc = wbase + (ck) * WCHUNK;                        \
        _Pragma("unroll") for (int k = 0; k < 9; ++k)                        \
            gl_lds16(wsrc + (k * 256 + tid) * 8, &sW[(k * 256 + tid) * 8]);  \
    }

#define COMPUTE()                                                            \
    {                                                                        \
        _Pragma("unroll") for (int tap = 0; tap < 9; ++tap) {                \
            const int dy = tap / 3, dxo = tap - dy * 3;                      \
            short8 a[4];                                                     \
            const ushort_t* wp_ = sW + tap * 2048 + abase;                   \
            _Pragma("unroll") for (int m = 0; m < 4; ++m)                    \
                a[m] = *(const short8*)(wp_ + m * 128);                      \
            _Pragma("unroll") for (int nt = 0; nt < 2; ++nt) {               \
                short8 bf = *(const short8*)&sIn[bb[nt] + (dy * LDSW + dxo) * SPAD]; \
                _Pragma("unroll") for (int m = 0; m < 4; ++m)                \
                    acc[m][nt] = __builtin_amdgcn_mfma_f32_16x16x32_bf16(    \
                        a[m], bf, acc[m][nt], 0, 0, 0);                      \
            }                                                                \
        }                                                                    \
    }

    short8 VA[2][3], VB[2][3];
    stage_load<CINV>(srcA, srcB, bstrB, 0, b, by, bx, tid, VA);
#pragma unroll
    for (int ck = 0; ck < NCH; ck += 2) {
        __syncthreads();
        if (ck + 1 < NCH)
            stage_load<CINV>(srcA, srcB, bstrB, ck + 1, b, by, bx, tid, VB);
        stage_write(sIn, tid, VA);
        STAGE_W(ck);
        __syncthreads();
        COMPUTE();
        if (ck + 1 < NCH) {
            __syncthreads();
            if (ck + 2 < NCH)
                stage_load<CINV>(srcA, srcB, bstrB, ck + 2, b, by, bx, tid, VA);
            stage_write(sIn, tid, VB);
            STAGE_W(ck + 1);
            __syncthreads();
            COMPUTE();
        }
    }

    // fused LSTM epilogue: m = gate (i,f,o,g)
#pragma unroll
    for (int nt = 0; nt < 2; ++nt) {
        int iy = by + wq * 2 + nt, ix = bx + x;
        int px = iy * 64 + ix;
#pragma unroll
        for (int r = 0; r < 4; ++r) {
            int hid = hg * 16 + q * 4 + r;
            int idx = (b * HID + hid) * PIX + px;
            float ig = sigm(acc[0][nt][r]);
            float fg = sigm(acc[1][nt][r]);
            float og = sigm(acc[2][nt][r]);
            float gg = tanh_fast(acc[3][nt][r]);
            float c = fg * cst[idx] + ig * gg;
            float h = og * tanh_fast(c);
            cst[idx] = c;
            hnext[(size_t)(b * HID + hid) * PIMG + (iy + 1) * HP + ix + 1] = f2b(h);
            if (out) out[(size_t)b * (16 * HID * PIX) + (size_t)hid * PIX + px] = h;
        }
    }
#undef STAGE_W
#undef COMPUTE
}

extern "C" void kernel_launch(void* const* d_in, const int* in_sizes, int n_in,
                              void* d_out, int out_size, void* d_ws, size_t ws_size,
                              hipStream_t stream) {
    const float* xf = (const float*)d_in[0];  // [4][16][1][64][64]
    const float* w0 = (const float*)d_in[1];  // [256][65][3][3]
    const float* b0 = (const float*)d_in[2];
    const float* w1 = (const float*)d_in[3];  // [256][128][3][3]
    const float* b1 = (const float*)d_in[4];
    float* out = (float*)d_out;               // [4][16][64][64][64]

    char* ws = (char*)d_ws;
    const size_t HBUF = (size_t)4 * HID * PIMG;       // 1,216,512 els
    ushort_t* h0a = (ushort_t*)ws;
    ushort_t* h0b = h0a + HBUF;
    ushort_t* h1a = h0b + HBUF;
    ushort_t* h1b = h1a + HBUF;
    ushort_t* xpad = h1b + HBUF;                      // 4*16*PIMG = 304,128 els
    float* c0 = (float*)(xpad + (size_t)4 * 16 * PIMG);
    float* c1 = c0 + (size_t)4 * HID * PIX;           // 1,048,576 f32 each
    ushort_t* Wp0 = (ushort_t*)(c1 + (size_t)4 * HID * PIX);  // 221,184 els
    ushort_t* Wp1 = Wp0 + 221184;                             // 294,912 els

    // zero h(x4, padded) + xpad + c0 + c1 : one contiguous region
    size_t zbytes = (4 * HBUF + (size_t)4 * 16 * PIMG) * sizeof(ushort_t) +
                    (size_t)2 * 4 * HID * PIX * sizeof(float);
    hipMemsetAsync(d_ws, 0, zbytes, stream);

    cvt_pad_x<<<262144 / 256, 256, 0, stream>>>(xf, xpad);
    pack_w<65, 3, true><<<221184 / 256, 256, 0, stream>>>(w0, Wp0, 221184);
    pack_w<128, 4, false><<<294912 / 256, 256, 0, stream>>>(w1, Wp1, 294912);

    dim3 grid(128, 4), blk(256);  // 512 blocks = 2/CU
    for (int t = 0; t < 16; ++t) {
        ushort_t* h0r = (t & 1) ? h0b : h0a;
        ushort_t* h0w = (t & 1) ? h0a : h0b;
        ushort_t* h1r = (t & 1) ? h1b : h1a;
        ushort_t* h1w = (t & 1) ? h1a : h1b;
        // layer0: channels [h0(64), x(1)] ; srcB = x plane for (b,t)
        cell_mfma<65, 3><<<grid, blk, 0, stream>>>(
            h0r, xpad + (size_t)t * PIMG, 16 * PIMG, Wp0, b0, c0, h0w, nullptr);
        // layer1: channels [h0(64), h1(64)]
        cell_mfma<128, 4><<<grid, blk, 0, stream>>>(
            h0w, h1r, HID * PIMG, Wp1, b1, c1, h1w,
            out + (size_t)t * HID * PIX);
    }
}